// Round 2
// baseline (1001.288 us; speedup 1.0000x reference)
//
#include <hip/hip_runtime.h>
#include <cfloat>

// Problem constants (x: [32,64,64,64] fp32, emb: [1024,64] fp32)
#define BATCH   32
#define CCH     64
#define HW      4096            // 64*64
#define NPIX    (BATCH * HW)    // 131072
#define KCODES  1024
#define NELEM   (NPIX * CCH)    // 8388608
#define EPS_AMBIG 1e-3f         // ~10x fp32 distance error bound

// Output layout (flat fp32): o[0..NELEM), loss[NELEM], indices[NELEM+1 ..)
// ws layout (fp32): wsf[0] = sumsq accumulator, wsf[256..256+KCODES) = ||e_k||^2

__global__ void vq_ee_kernel(const float* __restrict__ emb, float* __restrict__ wsf) {
    int k = blockIdx.x * blockDim.x + threadIdx.x;
    if (k == 0) wsf[0] = 0.f;                  // zero the sumsq accumulator (ws is poisoned)
    if (k < KCODES) {
        const float4* row = (const float4*)(emb + (size_t)k * CCH);
        float s = 0.f;
#pragma unroll
        for (int i = 0; i < CCH / 4; ++i) {
            float4 v = row[i];
            s = fmaf(v.x, v.x, s);
            s = fmaf(v.y, v.y, s);
            s = fmaf(v.z, v.z, s);
            s = fmaf(v.w, v.w, s);
        }
        wsf[256 + k] = s;
    }
}

__global__ __launch_bounds__(256) void vq_main_kernel(
    const float* __restrict__ x,
    const float* __restrict__ emb,
    const float* __restrict__ ee,      // wsf+256
    float* __restrict__ o,             // d_out
    float* __restrict__ idx_out,       // d_out + NELEM + 1
    float* __restrict__ sumsq_acc)     // wsf
{
    const int n = blockIdx.x * blockDim.x + threadIdx.x;   // pixel id
    const int b = n >> 12;          // n / 4096
    const int p = n & 4095;         // n % 4096
    const float* xb = x + (size_t)b * (CCH * HW) + p;

    // Load this pixel's channel vector into registers (coalesced across lanes per c)
    float z[CCH];
#pragma unroll
    for (int c = 0; c < CCH; ++c) z[c] = xb[c * HW];

    // Pass 1 (fp32): d_k = ||e_k||^2 - 2 z.e_k  (drop ||z||^2, const per pixel).
    // Track best, argmin (strict <  -> lowest index, matches np.argmin), and
    // second-best for ambiguity detection.
    float best = FLT_MAX, best2 = FLT_MAX;
    int bidx = 0;
#pragma unroll 2
    for (int k = 0; k < KCODES; ++k) {
        const float* ek = emb + k * CCH;   // wave-uniform address -> scalar loads
        float a0 = 0.f, a1 = 0.f, a2 = 0.f, a3 = 0.f;
#pragma unroll
        for (int c = 0; c < CCH; c += 4) {
            a0 = fmaf(z[c + 0], ek[c + 0], a0);
            a1 = fmaf(z[c + 1], ek[c + 1], a1);
            a2 = fmaf(z[c + 2], ek[c + 2], a2);
            a3 = fmaf(z[c + 3], ek[c + 3], a3);
        }
        float dist = fmaf(-2.f, (a0 + a1) + (a2 + a3), ee[k]);
        // second-best update trick: best2 = min(best2, max(dist, best))
        best2 = fminf(best2, fmaxf(dist, best));
        if (dist < best) { best = dist; bidx = k; }
    }

    // Ambiguity rescan: if the fp32 gap is under EPS, redo candidates in fp64
    // exact form sum((z-e)^2) -> true argmin (matches a high-precision ref).
    if (best2 - best < EPS_AMBIG) {
        const float cut = best + EPS_AMBIG;
        double best64 = DBL_MAX;
        int bi2 = 0;
        for (int k = 0; k < KCODES; ++k) {
            const float* ek = emb + k * CCH;
            float a0 = 0.f, a1 = 0.f, a2 = 0.f, a3 = 0.f;
#pragma unroll
            for (int c = 0; c < CCH; c += 4) {
                a0 = fmaf(z[c + 0], ek[c + 0], a0);
                a1 = fmaf(z[c + 1], ek[c + 1], a1);
                a2 = fmaf(z[c + 2], ek[c + 2], a2);
                a3 = fmaf(z[c + 3], ek[c + 3], a3);
            }
            float dist = fmaf(-2.f, (a0 + a1) + (a2 + a3), ee[k]);
            if (dist < cut) {               // rare: ~2 candidates per ambiguous lane
                double d64 = 0.0;
#pragma unroll
                for (int c = 0; c < CCH; ++c) {
                    double t = (double)z[c] - (double)ek[c];
                    d64 = fma(t, t, d64);
                }
                if (d64 < best64) { best64 = d64; bi2 = k; }
            }
        }
        bidx = bi2;
    }

    idx_out[n] = (float)bidx;

    // Gather chosen code, write o (numerically == e), accumulate (x-e)^2
    const float* ekb = emb + bidx * CCH;
    float* ob = o + (size_t)b * (CCH * HW) + p;
    float ss = 0.f;
#pragma unroll
    for (int c = 0; c < CCH; ++c) {
        float e = ekb[c];
        float d = z[c] - e;
        ss = fmaf(d, d, ss);
        ob[c * HW] = z[c] + (e - z[c]);
    }

    // Wave reduce (64 lanes) then block reduce, one atomic per block
    for (int off = 32; off > 0; off >>= 1)
        ss += __shfl_down(ss, off, 64);
    __shared__ float wsum[4];
    const int lane = threadIdx.x & 63;
    const int wid  = threadIdx.x >> 6;
    if (lane == 0) wsum[wid] = ss;
    __syncthreads();
    if (threadIdx.x == 0) {
        atomicAdd(sumsq_acc, (wsum[0] + wsum[1]) + (wsum[2] + wsum[3]));
    }
}

__global__ void vq_fin_kernel(const float* __restrict__ acc, float* __restrict__ loss) {
    *loss = 1.25f * (*acc) * (1.0f / (float)NELEM);
}

extern "C" void kernel_launch(void* const* d_in, const int* in_sizes, int n_in,
                              void* d_out, int out_size, void* d_ws, size_t ws_size,
                              hipStream_t stream) {
    const float* x   = (const float*)d_in[0];
    const float* emb = (const float*)d_in[1];
    float* out = (float*)d_out;
    float* wsf = (float*)d_ws;

    float* o_out    = out;                 // [32,64,64,64]
    float* loss_out = out + NELEM;         // scalar
    float* idx_out  = out + NELEM + 1;     // [32,64,64]
    float* ee       = wsf + 256;

    vq_ee_kernel<<<(KCODES + 255) / 256, 256, 0, stream>>>(emb, wsf);
    vq_main_kernel<<<NPIX / 256, 256, 0, stream>>>(x, emb, ee, o_out, idx_out, wsf);
    vq_fin_kernel<<<1, 1, 0, stream>>>(wsf, loss_out);
}

// Round 3
// 200.144 us; speedup vs baseline: 5.0028x; 5.0028x over previous
//
#include <hip/hip_runtime.h>

// VQ-VAE quantization, MFMA fp16-split version.
// x: [32,64,64,64] fp32, emb: [1024,64] fp32
#define BATCH   32
#define CCH     64
#define HW      4096
#define NPIX    (BATCH * HW)        // 131072
#define KCODES  1024
#define NELEM   (NPIX * CCH)        // 8388608
#define MB      128                 // pixels per block
#define RS      72                  // LDS row stride in f16 elems (64 + 8 pad)
#define CK      128                 // codes per LDS chunk
#define MARGIN_Q 8u                 // ambiguity margin in 1/2048 distance units

typedef _Float16 f16;
typedef __attribute__((ext_vector_type(8))) _Float16 f16x8;
typedef __attribute__((ext_vector_type(2))) _Float16 f16x2;
typedef __attribute__((ext_vector_type(4))) float    f32x4;

static __device__ __forceinline__ f32x4 mfma16(f16x8 a, f16x8 b, f32x4 c) {
    return __builtin_amdgcn_mfma_f32_16x16x32_f16(a, b, c, 0, 0, 0);
}

// ws layout (32-bit units): [0]=loss acc (f32), [1]=worklist count (u32),
// [256..1280) = eeb[k] = 2048*||e_k||^2 + 2^20 (f32), [2048..2048+cap) worklist (u32)

__global__ void vq_prep(const float* __restrict__ emb, float* __restrict__ wsf,
                        unsigned* __restrict__ wsu) {
    int k = blockIdx.x * blockDim.x + threadIdx.x;
    if (k == 0) { wsf[0] = 0.f; wsu[1] = 0u; }
    if (k < KCODES) {
        const float4* row = (const float4*)(emb + (size_t)k * CCH);
        float s = 0.f;
#pragma unroll
        for (int i = 0; i < CCH / 4; ++i) {
            float4 v = row[i];
            s = fmaf(v.x, v.x, s); s = fmaf(v.y, v.y, s);
            s = fmaf(v.z, v.z, s); s = fmaf(v.w, v.w, s);
        }
        wsf[256 + k] = fmaf(s, 2048.0f, 1048576.0f);   // 2048*ee + 2^20
    }
}

__global__ __launch_bounds__(256, 4) void vq_main(
    const float* __restrict__ x,
    const float* __restrict__ emb,
    const float* __restrict__ eeb,     // wsf + 256
    float* __restrict__ o,
    float* __restrict__ idx_out,
    float* __restrict__ acc,           // wsf[0]
    unsigned* __restrict__ wl_count,   // wsu[1]
    unsigned* __restrict__ wl,         // wsu + 2048
    unsigned cap)
{
    __shared__ f16 eH[MB * RS];        // phase0: z_hi; k-loop: e_hi chunk
    __shared__ f16 eL[MB * RS];        // phase0: z_lo; k-loop: e_lo chunk
    __shared__ float eebl[CK];
    __shared__ unsigned bu1[MB], bu2[MB];
    __shared__ float wred[4];

    const int t    = threadIdx.x;
    const int lane = t & 63;
    const int w    = t >> 6;           // wave id 0..3
    const int col  = lane & 15;        // MFMA m/n index
    const int quad = lane >> 4;        // MFMA k-quad
    const int n0   = blockIdx.x * MB;
    const int b    = n0 >> 12;
    const int p0   = n0 & 4095;
    const float* xb = x + (size_t)b * (CCH * HW) + p0;

    // ---- phase 0: stage zs = -2x, split to fp16 hi/lo, into eH/eL ----
    {
        const int pl = t & 127, c0 = t >> 7;
        for (int c = c0; c < CCH; c += 2) {
            float zs = -2.0f * xb[(size_t)c * HW + pl];
            f16 h = (f16)zs;
            f16 l = (f16)(zs - (float)h);
            eH[pl * RS + c] = h;
            eL[pl * RS + c] = l;
        }
    }
    __syncthreads();

    // ---- phase 0b: load A fragments (2 row-tiles x 2 k-chunks), keep in regs ----
    f16x8 aH[2][2], aL[2][2];
#pragma unroll
    for (int rt = 0; rt < 2; ++rt) {
        const int pl = w * 32 + rt * 16 + col;    // A: m = lane&15
#pragma unroll
        for (int kc = 0; kc < 2; ++kc) {
            const int off = pl * RS + kc * 32 + quad * 8;  // k = quad*8+j
            aH[rt][kc] = *(const f16x8*)&eH[off];
            aL[rt][kc] = *(const f16x8*)&eL[off];
        }
    }
    __syncthreads();

    unsigned best[8], best2[8];
#pragma unroll
    for (int s = 0; s < 8; ++s) { best[s] = 0xFFFFFFFFu; best2[s] = 0xFFFFFFFFu; }

    // ---- K loop: 8 chunks of 128 codes ----
    for (int chunk = 0; chunk < KCODES / CK; ++chunk) {
        const int k0 = chunk * CK;
        {   // stage codebook chunk, fp16 split
            const int cl = t >> 1, chv = (t & 1) * 32;
            const float* er = emb + (size_t)(k0 + cl) * CCH + chv;
#pragma unroll
            for (int i = 0; i < 32; i += 2) {
                float2 v = *(const float2*)&er[i];
                f16 h0 = (f16)v.x, h1 = (f16)v.y;
                f16 l0 = (f16)(v.x - (float)h0), l1 = (f16)(v.y - (float)h1);
                *(f16x2*)&eH[cl * RS + chv + i] = f16x2{h0, h1};
                *(f16x2*)&eL[cl * RS + chv + i] = f16x2{l0, l1};
            }
            if (t < CK) eebl[t] = eeb[k0 + t];
        }
        __syncthreads();

#pragma unroll
        for (int tile = 0; tile < CK / 16; ++tile) {
            const int roff = (tile * 16 + col) * RS;         // B: n = lane&15
            f16x8 bH0 = *(const f16x8*)&eH[roff + quad * 8];
            f16x8 bH1 = *(const f16x8*)&eH[roff + 32 + quad * 8];
            f16x8 bL0 = *(const f16x8*)&eL[roff + quad * 8];
            f16x8 bL1 = *(const f16x8*)&eL[roff + 32 + quad * 8];
            const float eebc = eebl[tile * 16 + col];
            const unsigned kidx = (unsigned)(k0 + tile * 16 + col);
#pragma unroll
            for (int rt = 0; rt < 2; ++rt) {
                f32x4 a4 = {0.f, 0.f, 0.f, 0.f};
                a4 = mfma16(aH[rt][0], bH0, a4);
                a4 = mfma16(aH[rt][1], bH1, a4);
                a4 = mfma16(aL[rt][0], bH0, a4);
                a4 = mfma16(aL[rt][1], bH1, a4);
                a4 = mfma16(aH[rt][0], bL0, a4);
                a4 = mfma16(aH[rt][1], bL1, a4);
#pragma unroll
                for (int r = 0; r < 4; ++r) {
                    float uf = fmaf(a4[r], 2048.0f, eebc);   // fixed-point dist
                    unsigned u = (unsigned)uf;
                    u = u > 0x1FFFFFu ? 0x1FFFFFu : u;
                    unsigned pk = (u << 10) | kidx;
                    const int s = rt * 4 + r;
                    unsigned mx = pk > best[s] ? pk : best[s];
                    best2[s] = best2[s] < mx ? best2[s] : mx;
                    best[s]  = best[s] < pk ? best[s] : pk;
                }
            }
        }
        __syncthreads();
    }

    // ---- cross-lane argmin reduce over the 16 code-columns ----
#pragma unroll
    for (int d = 1; d < 16; d <<= 1) {
#pragma unroll
        for (int s = 0; s < 8; ++s) {
            unsigned ob  = __shfl_xor(best[s],  d, 64);
            unsigned ob2 = __shfl_xor(best2[s], d, 64);
            unsigned mx  = best[s] > ob ? best[s] : ob;
            unsigned mn2 = best2[s] < ob2 ? best2[s] : ob2;
            best2[s] = mn2 < mx ? mn2 : mx;
            best[s]  = best[s] < ob ? best[s] : ob;
        }
    }
    if (col == 0) {
#pragma unroll
        for (int rt = 0; rt < 2; ++rt)
#pragma unroll
            for (int r = 0; r < 4; ++r) {
                const int pl = w * 32 + rt * 16 + quad * 4 + r;   // C/D row
                bu1[pl] = best[rt * 4 + r];
                bu2[pl] = best2[rt * 4 + r];
            }
    }
    __syncthreads();

    // ---- epilogue: indices, ambiguity worklist, o, loss ----
    if (t < MB) {
        const unsigned bu = bu1[t];
        idx_out[n0 + t] = (float)(bu & 1023u);
        const unsigned qg = (bu2[t] >> 10) - (bu >> 10);
        if (qg < MARGIN_Q) {
            unsigned pos = atomicAdd(wl_count, 1u);
            if (pos < cap) wl[pos] = (unsigned)(n0 + t);
        }
    }
    float ss = 0.f;
    {
        const int pl = t & 127, c0 = t >> 7;
        const unsigned bidx = bu1[pl] & 1023u;
        const float* er = emb + (size_t)bidx * CCH;
        float* ob = o + (size_t)b * (CCH * HW) + p0 + pl;
        for (int c = c0; c < CCH; c += 2) {
            float xv = xb[(size_t)c * HW + pl];
            float e  = er[c];
            ob[(size_t)c * HW] = xv + (e - xv);
            float d = xv - e;
            ss = fmaf(d, d, ss);
        }
    }
    for (int off = 32; off; off >>= 1) ss += __shfl_down(ss, off, 64);
    if (lane == 0) wred[w] = ss;
    __syncthreads();
    if (t == 0) atomicAdd(acc, (wred[0] + wred[1]) + (wred[2] + wred[3]));
}

// Exact fp64 refine for ambiguous pixels (one wave per pixel, grid-stride).
__global__ __launch_bounds__(256) void vq_refine(
    const float* __restrict__ x, const float* __restrict__ emb,
    float* __restrict__ o, float* __restrict__ idx_out,
    float* __restrict__ acc, const unsigned* __restrict__ wl_count,
    const unsigned* __restrict__ wl, unsigned cap)
{
    unsigned cnt = *wl_count; if (cnt > cap) cnt = cap;
    const int lane = threadIdx.x & 63;
    const unsigned wgid = blockIdx.x * 4 + (threadIdx.x >> 6);
    for (unsigned i = wgid; i < cnt; i += 128u * 4u) {
        const int n = (int)wl[i];
        const int b = n >> 12, p = n & 4095;
        const float* xb = x + (size_t)b * (CCH * HW) + p;
        float z[CCH];
#pragma unroll
        for (int c = 0; c < CCH; ++c) z[c] = xb[(size_t)c * HW];

        double bd = 1e300; int bi = 0;
        for (int kk = 0; kk < KCODES / 64; ++kk) {
            const int k = lane * (KCODES / 64) + kk;     // ascending in-lane
            const float* er = emb + (size_t)k * CCH;
            double d = 0.0;
#pragma unroll
            for (int c = 0; c < CCH; ++c) {
                double tt = (double)z[c] - (double)er[c];
                d = fma(tt, tt, d);
            }
            if (d < bd) { bd = d; bi = k; }
        }
        for (int dlt = 1; dlt < 64; dlt <<= 1) {
            double od = __shfl_xor(bd, dlt, 64);
            int    oi = __shfl_xor(bi, dlt, 64);
            if (od < bd || (od == bd && oi < bi)) { bd = od; bi = oi; }
        }
        const int old = (int)idx_out[n];
        if (bi != old) {
            if (lane == 0) idx_out[n] = (float)bi;
            // patch o and loss for this pixel (c = lane)
            const float xv = xb[(size_t)lane * HW];
            const float eo = emb[(size_t)old * CCH + lane];
            const float en = emb[(size_t)bi  * CCH + lane];
            o[(size_t)b * (CCH * HW) + (size_t)lane * HW + p] = xv + (en - xv);
            const float dn = xv - en, dold = xv - eo;
            float delta = fmaf(dn, dn, -dold * dold);
            for (int off = 32; off; off >>= 1) delta += __shfl_down(delta, off, 64);
            if (lane == 0) atomicAdd(acc, delta);
        }
    }
}

__global__ void vq_fin(const float* __restrict__ acc, float* __restrict__ loss) {
    *loss = 1.25f * (*acc) * (1.0f / (float)NELEM);
}

extern "C" void kernel_launch(void* const* d_in, const int* in_sizes, int n_in,
                              void* d_out, int out_size, void* d_ws, size_t ws_size,
                              hipStream_t stream) {
    const float* x   = (const float*)d_in[0];
    const float* emb = (const float*)d_in[1];
    float*    out = (float*)d_out;
    float*    wsf = (float*)d_ws;
    unsigned* wsu = (unsigned*)d_ws;

    float* o_out    = out;
    float* loss_out = out + NELEM;
    float* idx_out  = out + NELEM + 1;
    float* eeb      = wsf + 256;
    unsigned* wl    = wsu + 2048;
    unsigned cap = 0;
    if (ws_size / 4 > 2048) {
        size_t c = ws_size / 4 - 2048;
        cap = (unsigned)(c > NPIX ? NPIX : c);
    }

    vq_prep<<<4, 256, 0, stream>>>(emb, wsf, wsu);
    vq_main<<<NPIX / MB, 256, 0, stream>>>(x, emb, eeb, o_out, idx_out,
                                           wsf, wsu + 1, wl, cap);
    vq_refine<<<128, 256, 0, stream>>>(x, emb, o_out, idx_out, wsf,
                                       wsu + 1, wl, cap);
    vq_fin<<<1, 1, 0, stream>>>(wsf, loss_out);
}

// Round 4
// 171.081 us; speedup vs baseline: 5.8527x; 1.1699x over previous
//
#include <hip/hip_runtime.h>

// VQ-VAE quantization. x: [32,64,64,64] fp32, emb: [1024,64] fp32
#define BATCH   32
#define CCH     64
#define HW      4096
#define NPIX    (BATCH * HW)        // 131072
#define KCODES  1024
#define NELEM   (NPIX * CCH)        // 8388608
#define MB      128                 // pixels per block
#define CK      64                  // codes per LDS chunk (16 chunks)
#define MARGIN_Q 8u                 // ambiguity margin, 1/2048 distance units

typedef _Float16 f16;
typedef __attribute__((ext_vector_type(8))) _Float16 f16x8;
typedef __attribute__((ext_vector_type(4))) float    f32x4;

static __device__ __forceinline__ f32x4 mfma16(f16x8 a, f16x8 b, f32x4 c) {
    return __builtin_amdgcn_mfma_f32_16x16x32_f16(a, b, c, 0, 0, 0);
}

// async global->LDS, 16B per lane. LDS dest is wave-uniform base + lane*16.
static __device__ __forceinline__ void dma16(void* lds, const void* g) {
    __builtin_amdgcn_global_load_lds(
        (const __attribute__((address_space(1))) unsigned int*)g,
        (__attribute__((address_space(3))) unsigned int*)lds, 16, 0, 0);
}

// ws layout (bytes):
//   [0]      f32 loss accumulator
//   [4]      u32 worklist count
//   [256..4352)       eeb[k] = 2048*||e_k||^2 + 2^20  (1024 f32)
//   [8192..139264)    cbH: fp16 hi codebook, row r granule g at r*128 + (g^(r&7))*16
//   [139264..270336)  cbL: fp16 lo codebook, same swizzle
//   [270336..)        worklist (u32)
#define WS_EEB_F   64          // float index
#define WS_CBH_B   8192
#define WS_CBL_B   139264
#define WS_WL_U    67584       // u32 index

__global__ __launch_bounds__(256) void vq_prep(
    const float* __restrict__ emb, float* __restrict__ wsf,
    unsigned* __restrict__ wsu, f16* __restrict__ cbH, f16* __restrict__ cbL,
    float* __restrict__ eeb_g)
{
    const int t = threadIdx.x;
    if (blockIdx.x < 32) {
        const int gid = blockIdx.x * 256 + t;        // 0..8191 granules
        const int row = gid >> 3, gi = gid & 7;
        const float* src = emb + (size_t)row * CCH + gi * 8;
        float4 v0 = *(const float4*)(src);
        float4 v1 = *(const float4*)(src + 4);
        float vv[8] = {v0.x, v0.y, v0.z, v0.w, v1.x, v1.y, v1.z, v1.w};
        f16x8 h, l;
#pragma unroll
        for (int j = 0; j < 8; ++j) {
            f16 hh = (f16)vv[j];
            h[j] = hh;
            l[j] = (f16)(vv[j] - (float)hh);
        }
        const int off = row * 64 + 8 * (gi ^ (row & 7));
        *(f16x8*)(cbH + off) = h;
        *(f16x8*)(cbL + off) = l;
    } else {
        if (t == 0) { wsf[0] = 0.f; wsu[1] = 0u; }
        for (int r = t * 4; r < t * 4 + 4; ++r) {
            const float4* row4 = (const float4*)(emb + (size_t)r * CCH);
            float s = 0.f;
#pragma unroll
            for (int i = 0; i < 16; ++i) {
                float4 v = row4[i];
                s = fmaf(v.x, v.x, s); s = fmaf(v.y, v.y, s);
                s = fmaf(v.z, v.z, s); s = fmaf(v.w, v.w, s);
            }
            eeb_g[r] = fmaf(s, 2048.0f, 1048576.0f);
        }
    }
}

__global__ __launch_bounds__(256, 4) void vq_main(
    const float* __restrict__ x,
    const float* __restrict__ emb,
    const f16* __restrict__ cbH, const f16* __restrict__ cbL,
    const float* __restrict__ eeb_g,
    float* __restrict__ o, float* __restrict__ idx_out,
    float* __restrict__ acc, unsigned* __restrict__ wl_count,
    unsigned* __restrict__ wl, unsigned cap)
{
    // [0,16K): buf0 (H 8K | L 8K)   [16K,32K): buf1  — phase0 overlays z hi/lo
    __shared__ __align__(16) char smem[32768];
    __shared__ float eebl[2][CK];
    __shared__ unsigned bu1[MB], bu2[MB];
    __shared__ float wred[4];

    const int t    = threadIdx.x;
    const int lane = t & 63;
    const int w    = t >> 6;
    const int col  = lane & 15;
    const int quad = lane >> 4;
    const int c7   = col & 7;
    const int sw0  = 8 * (quad ^ c7);      // granule swizzle, chans 0..31
    const int sw1  = sw0 ^ 32;             // chans 32..63
    const int n0   = blockIdx.x * MB;
    const int b    = n0 >> 12;
    const int p0   = n0 & 4095;
    const float* xb = x + (size_t)b * (CCH * HW) + p0;

    f16* zH = (f16*)smem;                  // 128 rows x 64 f16 (swizzled)
    f16* zL = (f16*)(smem + 16384);

    // ---- phase 0: stage zs = -2x as fp16 hi/lo, swizzled ----
    {
        const int pl = t & 127;
        const int g0 = (t >> 7) * 4;
#pragma unroll
        for (int i = 0; i < 4; ++i) {
            const int g = g0 + i;
            f16x8 h, l;
#pragma unroll
            for (int j = 0; j < 8; ++j) {
                float zs = -2.0f * xb[(size_t)(g * 8 + j) * HW + pl];
                f16 hh = (f16)zs;
                h[j] = hh;
                l[j] = (f16)(zs - (float)hh);
            }
            const int off = pl * 64 + 8 * (g ^ (pl & 7));
            *(f16x8*)(zH + off) = h;
            *(f16x8*)(zL + off) = l;
        }
    }
    __syncthreads();

    // ---- phase 0b: A fragments to registers (2 row-tiles x 2 k-chunks) ----
    f16x8 aH[2][2], aL[2][2];
#pragma unroll
    for (int rt = 0; rt < 2; ++rt) {
        const int pl = w * 32 + rt * 16 + col;     // pl&7 == c7
        aH[rt][0] = *(const f16x8*)&zH[pl * 64 + sw0];
        aH[rt][1] = *(const f16x8*)&zH[pl * 64 + sw1];
        aL[rt][0] = *(const f16x8*)&zL[pl * 64 + sw0];
        aL[rt][1] = *(const f16x8*)&zL[pl * 64 + sw1];
    }
    __syncthreads();   // all waves done reading z before DMA overwrites

    unsigned best[8], best2[8];
#pragma unroll
    for (int s = 0; s < 8; ++s) { best[s] = 0xFFFFFFFFu; best2[s] = 0xFFFFFFFFu; }

    // DMA staging: wave w copies its 2KB slice of each 8KB (H and L) region
    auto stage = [&](int chunk, int bufi) {
        const int k0 = chunk * CK;
        char* lb = smem + bufi * 16384;
        const char* gH = (const char*)cbH + (size_t)k0 * 128 + w * 2048 + lane * 16;
        const char* gL = (const char*)cbL + (size_t)k0 * 128 + w * 2048 + lane * 16;
        char* lH = lb + w * 2048;
        char* lL = lb + 8192 + w * 2048;
        dma16(lH,        gH);
        dma16(lH + 1024, gH + 1024);
        dma16(lL,        gL);
        dma16(lL + 1024, gL + 1024);
        if (t < CK) eebl[bufi][t] = eeb_g[k0 + t];
    };

    stage(0, 0);

    for (int chunk = 0; chunk < KCODES / CK; ++chunk) {
        const int cur = chunk & 1;
        __syncthreads();                       // chunk's DMA visible to all
        if (chunk + 1 < KCODES / CK) stage(chunk + 1, cur ^ 1);

        const f16* bufH = (const f16*)(smem + cur * 16384);
        const f16* bufL = bufH + 4096;
        const int k0 = chunk * CK;

#pragma unroll
        for (int tile = 0; tile < CK / 16; ++tile) {
            const f16* bh = bufH + (tile * 16 + col) * 64;
            const f16* bl = bufL + (tile * 16 + col) * 64;
            f16x8 bH0 = *(const f16x8*)(bh + sw0);
            f16x8 bH1 = *(const f16x8*)(bh + sw1);
            f16x8 bL0 = *(const f16x8*)(bl + sw0);
            f16x8 bL1 = *(const f16x8*)(bl + sw1);
            const float eebc = eebl[cur][tile * 16 + col];
            const unsigned kb = (unsigned)(k0 + tile * 16 + col);
#pragma unroll
            for (int rt = 0; rt < 2; ++rt) {
                f32x4 a4 = {0.f, 0.f, 0.f, 0.f};
                a4 = mfma16(aH[rt][0], bH0, a4);
                a4 = mfma16(aH[rt][1], bH1, a4);
                a4 = mfma16(aL[rt][0], bH0, a4);
                a4 = mfma16(aL[rt][1], bH1, a4);
                a4 = mfma16(aH[rt][0], bL0, a4);
                a4 = mfma16(aH[rt][1], bL1, a4);
#pragma unroll
                for (int r = 0; r < 4; ++r) {
                    float uf = fmaf(a4[r], 2048.0f, eebc);   // in (0, 2^22)
                    unsigned pk = (((unsigned)uf) << 10) | kb;
                    const int s = rt * 4 + r;
                    unsigned mx = pk > best[s] ? pk : best[s];
                    best2[s] = best2[s] < mx ? best2[s] : mx;
                    best[s]  = best[s] < pk ? best[s] : pk;
                }
            }
        }
    }

    // ---- cross-lane argmin reduce over the 16 code-columns ----
#pragma unroll
    for (int d = 1; d < 16; d <<= 1) {
#pragma unroll
        for (int s = 0; s < 8; ++s) {
            unsigned ob  = __shfl_xor(best[s],  d, 64);
            unsigned ob2 = __shfl_xor(best2[s], d, 64);
            unsigned mx  = best[s] > ob ? best[s] : ob;
            unsigned mn2 = best2[s] < ob2 ? best2[s] : ob2;
            best2[s] = mn2 < mx ? mn2 : mx;
            best[s]  = best[s] < ob ? best[s] : ob;
        }
    }
    if (col == 0) {
#pragma unroll
        for (int rt = 0; rt < 2; ++rt)
#pragma unroll
            for (int r = 0; r < 4; ++r) {
                const int pl = w * 32 + rt * 16 + quad * 4 + r;
                bu1[pl] = best[rt * 4 + r];
                bu2[pl] = best2[rt * 4 + r];
            }
    }
    __syncthreads();

    // ---- epilogue: indices, worklist, o, loss ----
    if (t < MB) {
        const unsigned bu = bu1[t];
        idx_out[n0 + t] = (float)(bu & 1023u);
        const unsigned qg = (bu2[t] >> 10) - (bu >> 10);
        if (qg < MARGIN_Q) {
            unsigned pos = atomicAdd(wl_count, 1u);
            if (pos < cap) wl[pos] = (unsigned)(n0 + t);
        }
    }
    float ss = 0.f;
    {
        const int pl = t & 127, cs = t >> 7;
        const unsigned bidx = bu1[pl] & 1023u;
        const float* er = emb + (size_t)bidx * CCH;
        float* ob = o + (size_t)b * (CCH * HW) + p0 + pl;
        for (int c = cs; c < CCH; c += 2) {
            float xv = xb[(size_t)c * HW + pl];
            float e  = er[c];
            ob[(size_t)c * HW] = xv + (e - xv);
            float d = xv - e;
            ss = fmaf(d, d, ss);
        }
    }
    for (int off = 32; off; off >>= 1) ss += __shfl_down(ss, off, 64);
    if (lane == 0) wred[w] = ss;
    __syncthreads();
    if (t == 0) atomicAdd(acc, (wred[0] + wred[1]) + (wred[2] + wred[3]));
}

// Exact fp64 refine: one BLOCK per ambiguous pixel, 4 codes per thread.
__global__ __launch_bounds__(256) void vq_refine(
    const float* __restrict__ x, const float* __restrict__ emb,
    float* __restrict__ o, float* __restrict__ idx_out,
    float* __restrict__ acc, const unsigned* __restrict__ wl_count,
    const unsigned* __restrict__ wl, unsigned cap)
{
    __shared__ float zsh[CCH];
    __shared__ double rbd[4];
    __shared__ int rbi[4];
    __shared__ int s_pk;
    unsigned cnt = *wl_count; if (cnt > cap) cnt = cap;
    const int t = threadIdx.x;

    for (unsigned i = blockIdx.x; i < cnt; i += gridDim.x) {
        const int n = (int)wl[i];
        const int b = n >> 12, p = n & 4095;
        if (t < CCH) zsh[t] = x[(size_t)b * (CCH * HW) + (size_t)t * HW + p];
        __syncthreads();

        double bd = 1e300; int bi = KCODES;
        for (int j = 0; j < 4; ++j) {
            const int k = t + j * 256;             // ascending per thread
            const float* er = emb + (size_t)k * CCH;
            double d = 0.0;
#pragma unroll
            for (int c = 0; c < CCH; ++c) {
                double tt = (double)zsh[c] - (double)er[c];
                d = fma(tt, tt, d);
            }
            if (d < bd) { bd = d; bi = k; }
        }
        for (int dlt = 1; dlt < 64; dlt <<= 1) {
            double od = __shfl_xor(bd, dlt, 64);
            int    oi = __shfl_xor(bi, dlt, 64);
            if (od < bd || (od == bd && oi < bi)) { bd = od; bi = oi; }
        }
        const int wv = t >> 6;
        if ((t & 63) == 0) { rbd[wv] = bd; rbi[wv] = bi; }
        __syncthreads();
        if (t == 0) {
            double fb = rbd[0]; int fi = rbi[0];
            for (int q = 1; q < 4; ++q)
                if (rbd[q] < fb || (rbd[q] == fb && rbi[q] < fi)) { fb = rbd[q]; fi = rbi[q]; }
            const int old = (int)idx_out[n];
            if (fi != old) { idx_out[n] = (float)fi; s_pk = (old << 16) | fi; }
            else s_pk = -1;
        }
        __syncthreads();
        const int pk = s_pk;
        if (pk >= 0 && t < CCH) {                   // wave 0 only, uniform branch
            const int old = pk >> 16, fi = pk & 0xFFFF;
            const float xv = zsh[t];
            const float eo = emb[(size_t)old * CCH + t];
            const float en = emb[(size_t)fi  * CCH + t];
            o[(size_t)b * (CCH * HW) + (size_t)t * HW + p] = xv + (en - xv);
            const float dn = xv - en, dd = xv - eo;
            float delta = dn * dn - dd * dd;
            for (int off = 32; off; off >>= 1) delta += __shfl_down(delta, off, 64);
            if (t == 0) atomicAdd(acc, delta);
        }
        __syncthreads();
    }
}

__global__ void vq_fin(const float* __restrict__ acc, float* __restrict__ loss) {
    *loss = 1.25f * (*acc) * (1.0f / (float)NELEM);
}

extern "C" void kernel_launch(void* const* d_in, const int* in_sizes, int n_in,
                              void* d_out, int out_size, void* d_ws, size_t ws_size,
                              hipStream_t stream) {
    const float* x   = (const float*)d_in[0];
    const float* emb = (const float*)d_in[1];
    float*    out = (float*)d_out;
    float*    wsf = (float*)d_ws;
    unsigned* wsu = (unsigned*)d_ws;
    char*     wsb = (char*)d_ws;

    float* o_out    = out;
    float* loss_out = out + NELEM;
    float* idx_out  = out + NELEM + 1;
    float* eeb_g    = wsf + WS_EEB_F;
    f16*   cbH      = (f16*)(wsb + WS_CBH_B);
    f16*   cbL      = (f16*)(wsb + WS_CBL_B);
    unsigned* wl    = wsu + WS_WL_U;
    unsigned cap = 0;
    if (ws_size / 4 > WS_WL_U) {
        size_t c = ws_size / 4 - WS_WL_U;
        cap = (unsigned)(c > NPIX ? NPIX : c);
    }

    vq_prep<<<33, 256, 0, stream>>>(emb, wsf, wsu, cbH, cbL, eeb_g);
    vq_main<<<NPIX / MB, 256, 0, stream>>>(x, emb, cbH, cbL, eeb_g, o_out,
                                           idx_out, wsf, wsu + 1, wl, cap);
    vq_refine<<<512, 256, 0, stream>>>(x, emb, o_out, idx_out, wsf,
                                       wsu + 1, wl, cap);
    vq_fin<<<1, 1, 0, stream>>>(wsf, loss_out);
}

// Round 5
// 159.263 us; speedup vs baseline: 6.2870x; 1.0742x over previous
//
#include <hip/hip_runtime.h>

// VQ-VAE quantization. x: [32,64,64,64] fp32, emb: [1024,64] fp32
#define BATCH   32
#define CCH     64
#define HW      4096
#define NPIX    (BATCH * HW)        // 131072
#define KCODES  1024
#define NELEM   (NPIX * CCH)        // 8388608
#define MB      256                 // pixels per block (64 per wave, 4 row-tiles)
#define CK      64                  // codes per LDS chunk (16 chunks)
#define MARGIN_Q 3u                 // ambiguity margin, 1/2048 distance units

typedef _Float16 f16;
typedef __attribute__((ext_vector_type(8))) _Float16 f16x8;
typedef __attribute__((ext_vector_type(4))) float    f32x4;

static __device__ __forceinline__ f32x4 mfma16(f16x8 a, f16x8 b, f32x4 c) {
    return __builtin_amdgcn_mfma_f32_16x16x32_f16(a, b, c, 0, 0, 0);
}

static __device__ __forceinline__ void dma16(void* lds, const void* g) {
    __builtin_amdgcn_global_load_lds(
        (const __attribute__((address_space(1))) unsigned int*)g,
        (__attribute__((address_space(3))) unsigned int*)lds, 16, 0, 0);
}

// ws layout (bytes):
//   [0] f32 loss acc   [4] u32 worklist count
//   [256..4352)       eeb[k] = 2048*||e_k||^2 + 2^20  (1024 f32)
//   [8192..139264)    cbH swizzled fp16-hi codebook (row r granule g at r*64 + 8*(g^(r&7)))
//   [139264..270336)  cbL fp16-lo, same swizzle
//   [270336..)        worklist (u32)
#define WS_EEB_F   64
#define WS_CBH_B   8192
#define WS_CBL_B   139264
#define WS_WL_U    67584

__global__ __launch_bounds__(256) void vq_prep(
    const float* __restrict__ emb, float* __restrict__ wsf,
    unsigned* __restrict__ wsu, f16* __restrict__ cbH, f16* __restrict__ cbL,
    float* __restrict__ eeb_g)
{
    const int t = threadIdx.x;
    if (blockIdx.x < 32) {
        const int gid = blockIdx.x * 256 + t;        // 0..8191 granules
        const int row = gid >> 3, gi = gid & 7;
        const float* src = emb + (size_t)row * CCH + gi * 8;
        float4 v0 = *(const float4*)(src);
        float4 v1 = *(const float4*)(src + 4);
        float vv[8] = {v0.x, v0.y, v0.z, v0.w, v1.x, v1.y, v1.z, v1.w};
        f16x8 h, l;
#pragma unroll
        for (int j = 0; j < 8; ++j) {
            f16 hh = (f16)vv[j];
            h[j] = hh;
            l[j] = (f16)(vv[j] - (float)hh);
        }
        const int off = row * 64 + 8 * (gi ^ (row & 7));
        *(f16x8*)(cbH + off) = h;
        *(f16x8*)(cbL + off) = l;
    } else {
        if (t == 0) { wsf[0] = 0.f; wsu[1] = 0u; }
        for (int r = t * 4; r < t * 4 + 4; ++r) {
            const float4* row4 = (const float4*)(emb + (size_t)r * CCH);
            float s = 0.f;
#pragma unroll
            for (int i = 0; i < 16; ++i) {
                float4 v = row4[i];
                s = fmaf(v.x, v.x, s); s = fmaf(v.y, v.y, s);
                s = fmaf(v.z, v.z, s); s = fmaf(v.w, v.w, s);
            }
            eeb_g[r] = fmaf(s, 2048.0f, 1048576.0f);
        }
    }
}

__global__ __launch_bounds__(256, 2) void vq_main(
    const float* __restrict__ x,
    const float* __restrict__ emb,
    const f16* __restrict__ cbH, const f16* __restrict__ cbL,
    const float* __restrict__ eeb_g,
    float* __restrict__ o, float* __restrict__ idx_out,
    float* __restrict__ acc, unsigned* __restrict__ wl_count,
    unsigned* __restrict__ wl, unsigned cap)
{
    __shared__ __align__(16) char smem[32768];      // 2 x (8K H | 8K L)
    __shared__ float eebl[2][CK];
    __shared__ unsigned bu1[MB], bu2[MB];
    __shared__ float wred[4];

    const int t    = threadIdx.x;
    const int lane = t & 63;
    const int w    = t >> 6;
    const int col  = lane & 15;
    const int quad = lane >> 4;
    const int c7   = col & 7;
    const int sw0  = 8 * (quad ^ c7);      // swizzled granule offset, chans 0..31
    const int sw1  = sw0 ^ 32;             // chans 32..63
    const int n0   = blockIdx.x * MB;
    const int b    = n0 >> 12;
    const int p0   = n0 & 4095;
    const float* xb = x + (size_t)b * (CCH * HW) + p0;

    // wave w stages its 2KB slice of each 8KB H/L region
    auto stage = [&](int chunk, int bufi) {
        const int k0 = chunk * CK;
        char* lb = smem + bufi * 16384;
        const char* gH = (const char*)cbH + (size_t)k0 * 128 + w * 2048 + lane * 16;
        const char* gL = (const char*)cbL + (size_t)k0 * 128 + w * 2048 + lane * 16;
        char* lH = lb + w * 2048;
        char* lL = lb + 8192 + w * 2048;
        dma16(lH,        gH);
        dma16(lH + 1024, gH + 1024);
        dma16(lL,        gL);
        dma16(lL + 1024, gL + 1024);
        if (t < CK) eebl[bufi][t] = eeb_g[k0 + t];
    };

    stage(0, 0);    // DMA in flight while we build A fragments

    // ---- A fragments straight from global (MFMA A-layout, no LDS trip) ----
    // lane holds pixel (w*64 + rt*16 + col), chans kc*32 + quad*8 + j
    f16x8 aH[4][2], aL[4][2];
#pragma unroll
    for (int rt = 0; rt < 4; ++rt) {
        const int pp = w * 64 + rt * 16 + col;
#pragma unroll
        for (int kc = 0; kc < 2; ++kc) {
            f16x8 h, l;
#pragma unroll
            for (int j = 0; j < 8; ++j) {
                const int c = kc * 32 + quad * 8 + j;
                float zs = -2.0f * xb[(size_t)c * HW + pp];
                f16 hh = (f16)zs;
                h[j] = hh;
                l[j] = (f16)(zs - (float)hh);
            }
            aH[rt][kc] = h;
            aL[rt][kc] = l;
        }
    }

    unsigned best[16], best2[16];
#pragma unroll
    for (int s = 0; s < 16; ++s) { best[s] = 0xFFFFFFFFu; best2[s] = 0xFFFFFFFFu; }

    for (int chunk = 0; chunk < KCODES / CK; ++chunk) {
        const int cur = chunk & 1;
        __syncthreads();                        // chunk's DMA visible to all
        if (chunk + 1 < KCODES / CK) stage(chunk + 1, cur ^ 1);

        const f16* bufH = (const f16*)(smem + cur * 16384);
        const f16* bufL = bufH + 4096;
        const int k0 = chunk * CK;

#pragma unroll
        for (int tile = 0; tile < CK / 16; ++tile) {
            const f16* bh = bufH + (tile * 16 + col) * 64;
            const f16* bl = bufL + (tile * 16 + col) * 64;
            f16x8 bH0 = *(const f16x8*)(bh + sw0);
            f16x8 bH1 = *(const f16x8*)(bh + sw1);
            f16x8 bL0 = *(const f16x8*)(bl + sw0);
            f16x8 bL1 = *(const f16x8*)(bl + sw1);
            const float eebc = eebl[cur][tile * 16 + col];
            const unsigned kb = (unsigned)(k0 + tile * 16 + col);
#pragma unroll
            for (int rt = 0; rt < 4; ++rt) {
                f32x4 a4 = {0.f, 0.f, 0.f, 0.f};
                a4 = mfma16(aH[rt][0], bH0, a4);
                a4 = mfma16(aH[rt][1], bH1, a4);
                a4 = mfma16(aL[rt][0], bH0, a4);
                a4 = mfma16(aL[rt][1], bH1, a4);
                a4 = mfma16(aH[rt][0], bL0, a4);
                a4 = mfma16(aH[rt][1], bL1, a4);
#pragma unroll
                for (int r = 0; r < 4; ++r) {
                    float uf = fmaf(a4[r], 2048.0f, eebc);   // in (0, 2^22)
                    unsigned pk = (((unsigned)uf) << 10) | kb;
                    const int s = rt * 4 + r;
                    best2[s] = min(best2[s], max(pk, best[s]));
                    best[s]  = min(best[s], pk);
                }
            }
        }
    }

    // ---- cross-lane argmin reduce over the 16 code-columns ----
#pragma unroll
    for (int d = 1; d < 16; d <<= 1) {
#pragma unroll
        for (int s = 0; s < 16; ++s) {
            unsigned ob  = __shfl_xor(best[s],  d, 64);
            unsigned ob2 = __shfl_xor(best2[s], d, 64);
            best2[s] = min(min(best2[s], ob2), max(best[s], ob));
            best[s]  = min(best[s], ob);
        }
    }
    if (col == 0) {
#pragma unroll
        for (int rt = 0; rt < 4; ++rt)
#pragma unroll
            for (int r = 0; r < 4; ++r) {
                const int pl = w * 64 + rt * 16 + quad * 4 + r;   // C/D row map
                bu1[pl] = best[rt * 4 + r];
                bu2[pl] = best2[rt * 4 + r];
            }
    }
    __syncthreads();

    // ---- epilogue: one pixel per thread ----
    const unsigned bu = bu1[t];
    const unsigned bidx = bu & 1023u;
    idx_out[n0 + t] = (float)bidx;
    {
        const unsigned qg = (bu2[t] >> 10) - (bu >> 10);
        if (qg < MARGIN_Q) {
            unsigned pos = atomicAdd(wl_count, 1u);
            if (pos < cap) wl[pos] = (unsigned)(n0 + t);
        }
    }
    float ss = 0.f;
    {
        const float4* er4 = (const float4*)(emb + (size_t)bidx * CCH);
        const float* xbt = xb + t;
        float* ob = o + (size_t)b * (CCH * HW) + p0 + t;
#pragma unroll
        for (int i = 0; i < 16; ++i) {
            float4 ev = er4[i];
            float evv[4] = {ev.x, ev.y, ev.z, ev.w};
#pragma unroll
            for (int q = 0; q < 4; ++q) {
                const int c = i * 4 + q;
                float xv = xbt[(size_t)c * HW];
                float e  = evv[q];
                ob[(size_t)c * HW] = xv + (e - xv);
                float d = xv - e;
                ss = fmaf(d, d, ss);
            }
        }
    }
    for (int off = 32; off; off >>= 1) ss += __shfl_down(ss, off, 64);
    if (lane == 0) wred[w] = ss;
    __syncthreads();
    if (t == 0) atomicAdd(acc, (wred[0] + wred[1]) + (wred[2] + wred[3]));
}

// Exact fp64 refine: one BLOCK per ambiguous pixel, 4 codes per thread.
__global__ __launch_bounds__(256) void vq_refine(
    const float* __restrict__ x, const float* __restrict__ emb,
    float* __restrict__ o, float* __restrict__ idx_out,
    float* __restrict__ acc, const unsigned* __restrict__ wl_count,
    const unsigned* __restrict__ wl, unsigned cap)
{
    __shared__ float zsh[CCH];
    __shared__ double rbd[4];
    __shared__ int rbi[4];
    __shared__ int s_pk;
    unsigned cnt = *wl_count; if (cnt > cap) cnt = cap;
    const int t = threadIdx.x;

    for (unsigned i = blockIdx.x; i < cnt; i += gridDim.x) {
        const int n = (int)wl[i];
        const int b = n >> 12, p = n & 4095;
        if (t < CCH) zsh[t] = x[(size_t)b * (CCH * HW) + (size_t)t * HW + p];
        __syncthreads();

        double bd = 1e300; int bi = KCODES;
        for (int j = 0; j < 4; ++j) {
            const int k = t + j * 256;
            const float* er = emb + (size_t)k * CCH;
            double d = 0.0;
#pragma unroll
            for (int c = 0; c < CCH; ++c) {
                double tt = (double)zsh[c] - (double)er[c];
                d = fma(tt, tt, d);
            }
            if (d < bd) { bd = d; bi = k; }
        }
        for (int dlt = 1; dlt < 64; dlt <<= 1) {
            double od = __shfl_xor(bd, dlt, 64);
            int    oi = __shfl_xor(bi, dlt, 64);
            if (od < bd || (od == bd && oi < bi)) { bd = od; bi = oi; }
        }
        const int wv = t >> 6;
        if ((t & 63) == 0) { rbd[wv] = bd; rbi[wv] = bi; }
        __syncthreads();
        if (t == 0) {
            double fb = rbd[0]; int fi = rbi[0];
            for (int q = 1; q < 4; ++q)
                if (rbd[q] < fb || (rbd[q] == fb && rbi[q] < fi)) { fb = rbd[q]; fi = rbi[q]; }
            const int old = (int)idx_out[n];
            if (fi != old) { idx_out[n] = (float)fi; s_pk = (old << 16) | fi; }
            else s_pk = -1;
        }
        __syncthreads();
        const int pk = s_pk;
        if (pk >= 0 && t < CCH) {
            const int old = pk >> 16, fi = pk & 0xFFFF;
            const float xv = zsh[t];
            const float eo = emb[(size_t)old * CCH + t];
            const float en = emb[(size_t)fi  * CCH + t];
            o[(size_t)b * (CCH * HW) + (size_t)t * HW + p] = xv + (en - xv);
            const float dn = xv - en, dd = xv - eo;
            float delta = dn * dn - dd * dd;
            for (int off = 32; off; off >>= 1) delta += __shfl_down(delta, off, 64);
            if (t == 0) atomicAdd(acc, delta);
        }
        __syncthreads();
    }
}

__global__ void vq_fin(const float* __restrict__ acc, float* __restrict__ loss) {
    *loss = 1.25f * (*acc) * (1.0f / (float)NELEM);
}

extern "C" void kernel_launch(void* const* d_in, const int* in_sizes, int n_in,
                              void* d_out, int out_size, void* d_ws, size_t ws_size,
                              hipStream_t stream) {
    const float* x   = (const float*)d_in[0];
    const float* emb = (const float*)d_in[1];
    float*    out = (float*)d_out;
    float*    wsf = (float*)d_ws;
    unsigned* wsu = (unsigned*)d_ws;
    char*     wsb = (char*)d_ws;

    float* o_out    = out;
    float* loss_out = out + NELEM;
    float* idx_out  = out + NELEM + 1;
    float* eeb_g    = wsf + WS_EEB_F;
    f16*   cbH      = (f16*)(wsb + WS_CBH_B);
    f16*   cbL      = (f16*)(wsb + WS_CBL_B);
    unsigned* wl    = wsu + WS_WL_U;
    unsigned cap = 0;
    if (ws_size / 4 > WS_WL_U) {
        size_t c = ws_size / 4 - WS_WL_U;
        cap = (unsigned)(c > NPIX ? NPIX : c);
    }

    vq_prep<<<33, 256, 0, stream>>>(emb, wsf, wsu, cbH, cbL, eeb_g);
    vq_main<<<NPIX / MB, 256, 0, stream>>>(x, emb, cbH, cbL, eeb_g, o_out,
                                           idx_out, wsf, wsu + 1, wl, cap);
    vq_refine<<<512, 256, 0, stream>>>(x, emb, o_out, idx_out, wsf,
                                       wsu + 1, wl, cap);
    vq_fin<<<1, 1, 0, stream>>>(wsf, loss_out);
}